// Round 11
// baseline (255.561 us; speedup 1.0000x reference)
//
#include <hip/hip_runtime.h>
#include <hip/hip_bf16.h>
#include <cstdint>
#include <cstddef>

typedef __attribute__((ext_vector_type(8))) short short8;
typedef __attribute__((ext_vector_type(4))) short short4v;
typedef __attribute__((ext_vector_type(4))) float floatx4;
typedef __attribute__((ext_vector_type(16))) float floatx16;
typedef unsigned short ushort_t;
typedef unsigned long long u64_t;

#define LOG2E 1.44269504088896340736f

__device__ __forceinline__ unsigned short f2bf(float f) {
    unsigned u = __float_as_uint(f);
    u += 0x7FFFu + ((u >> 16) & 1u);   // RNE
    return (unsigned short)(u >> 16);
}
__device__ __forceinline__ float bf2f(unsigned short s) {
    return __uint_as_float(((unsigned)s) << 16);
}

// ---------------------------------------------------------------------------
// adjpack v3: FILL-SHAPED dedicated byte-pack.  The untested cell of the
// {dedicated,fused} x {ballot,lane-local} matrix.  Every prior adj reader
// hit ~2.2 TB/s; the harness fill (256-thr blocks, no LDS, lane-local) hits
// 6.9 TB/s.  This kernel is the fill's read-mirror:
//   256-thr blocks, ZERO LDS, tiny VGPR -> 8 blocks/CU;
//   thread packs 1 byte/iter = 8 consecutive ints (2x int4, dense 32B/lane;
//   wave spans dense 2KB -- NOT R10's 256B-stride 64-line scatter);
//   8 grid-stride iters, unroll-2 (4 int4 in flight/thread, ~128KB/CU).
// Byte bI of adjb = flat adj ints [8*bI, 8*bI+8), bit e = (int != 0);
// little-endian-consistent with attn's u64/uint2 reads (R9-proven).
// ---------------------------------------------------------------------------
__global__ __launch_bounds__(256) void adjpack(const int* __restrict__ adj,
                                               unsigned char* __restrict__ ab) {
    const size_t base = (size_t)blockIdx.x * 256 + threadIdx.x;   // byte index
#pragma unroll 2
    for (int k = 0; k < 8; ++k) {
        const size_t bI = base + (size_t)k * (2048 * 256);        // 524288 stride
        const int* ap = adj + bI * 8;
        int4 a0 = *(const int4*)(ap);
        int4 a1 = *(const int4*)(ap + 4);
        unsigned v = (a0.x != 0 ? 1u : 0u)   | (a0.y != 0 ? 2u : 0u)  |
                     (a0.z != 0 ? 4u : 0u)   | (a0.w != 0 ? 8u : 0u)  |
                     (a1.x != 0 ? 16u : 0u)  | (a1.y != 0 ? 32u : 0u) |
                     (a1.z != 0 ? 64u : 0u)  | (a1.w != 0 ? 128u : 0u);
        ab[bI] = (unsigned char)v;
    }
}

// ---------------------------------------------------------------------------
// gemm_h (R10-passed body, standalone): hT[b][o][j] = sum_k x[b][j][k]*W[o][k]
// (bf16, o-major).  Block = 64 j x 256 o, 1024 threads, 16 waves.
// af[8] x-register prologue + W-only LDS quarter staging (fp32->bf16 in
// stage).  Epilogue: o-major hT store + s_src/s_dst cross-wave reduction.
// ---------------------------------------------------------------------------
__global__ __launch_bounds__(1024) void gemm_h(const float* __restrict__ x,
                                               const float* __restrict__ W,
                                               ushort_t* __restrict__ hT,
                                               const float* __restrict__ a_src,
                                               const float* __restrict__ a_dst,
                                               float* __restrict__ s_src,
                                               float* __restrict__ s_dst) {
    __shared__ ushort_t wt[256][72];   // W quarter: 256 o x 64 k (+8 pad)
    __shared__ float sred[2][4][64];

    const int tid = threadIdx.x;
    const int w = tid >> 6, lane = tid & 63;
    const int bid = blockIdx.x;
    const int q = lane >> 4, t16 = lane & 15;
    const int jg = w >> 2, og = w & 3;

    // load this wave's 16 x-rows (fp32 -> bf16 A-frags, all K upfront)
    const int jrow = bid * 64 + jg * 16 + t16;
    const float* xr = x + (size_t)jrow * 256 + q * 8;
    short8 af[8];
#pragma unroll
    for (int kb = 0; kb < 8; ++kb) {
        float4 v0 = *(const float4*)(xr + kb * 32);
        float4 v1 = *(const float4*)(xr + kb * 32 + 4);
        short8 a;
        a[0] = (short)f2bf(v0.x); a[1] = (short)f2bf(v0.y);
        a[2] = (short)f2bf(v0.z); a[3] = (short)f2bf(v0.w);
        a[4] = (short)f2bf(v1.x); a[5] = (short)f2bf(v1.y);
        a[6] = (short)f2bf(v1.z); a[7] = (short)f2bf(v1.w);
        af[kb] = a;
    }

    floatx4 acc[4] = {};
#pragma unroll
    for (int kp = 0; kp < 4; ++kp) {
        if (kp) __syncthreads();       // protect wt overwrite
        // stage W K-quarter (fp32 -> bf16), 16 ushorts/thread
#pragma unroll
        for (int r = 0; r < 2; ++r) {
            int G = tid + 1024 * r;
            int row = G >> 3, g = G & 7;
            const float* wsrc = W + (size_t)row * 256 + kp * 64 + g * 8;
            float4 f0 = *(const float4*)(wsrc);
            float4 f1 = *(const float4*)(wsrc + 4);
            short8 wv;
            wv[0] = (short)f2bf(f0.x); wv[1] = (short)f2bf(f0.y);
            wv[2] = (short)f2bf(f0.z); wv[3] = (short)f2bf(f0.w);
            wv[4] = (short)f2bf(f1.x); wv[5] = (short)f2bf(f1.y);
            wv[6] = (short)f2bf(f1.z); wv[7] = (short)f2bf(f1.w);
            *(short8*)(&wt[row][g * 8]) = wv;
        }
        __syncthreads();
#pragma unroll
        for (int ks = 0; ks < 2; ++ks) {
#pragma unroll
            for (int ct = 0; ct < 4; ++ct) {
                short8 bf = *(const short8*)(&wt[og * 64 + ct * 16 + t16][ks * 32 + q * 8]);
                acc[ct] = __builtin_amdgcn_mfma_f32_16x16x32_bf16(af[kp * 2 + ks], bf, acc[ct], 0, 0, 0);
            }
        }
    }

    // hT store: D col=t16 -> o_local, row=q*4+r -> j_local  (o-major layout)
    const int jbase = bid * 64 + jg * 16 + q * 4;   // flat b*2048+j
    const int b = jbase >> 11, jj = jbase & 2047;
#pragma unroll
    for (int ct = 0; ct < 4; ++ct) {
        const int o = og * 64 + ct * 16 + t16;
        short4v sv;
        sv[0] = (short)f2bf(acc[ct][0]);
        sv[1] = (short)f2bf(acc[ct][1]);
        sv[2] = (short)f2bf(acc[ct][2]);
        sv[3] = (short)f2bf(acc[ct][3]);
        *(short4v*)(hT + ((size_t)b * 256 + o) * 2048 + jj) = sv;
    }

    // s_src/s_dst partials (this wave's 64 o), 16-lane shuffle
    float psv[4] = {}, pdv[4] = {};
#pragma unroll
    for (int ct = 0; ct < 4; ++ct) {
        const int o = og * 64 + ct * 16 + t16;
        float as = a_src[o], ad = a_dst[o];
#pragma unroll
        for (int r = 0; r < 4; ++r) {
            psv[r] = __fmaf_rn(acc[ct][r], as, psv[r]);
            pdv[r] = __fmaf_rn(acc[ct][r], ad, pdv[r]);
        }
    }
#pragma unroll
    for (int m = 1; m < 16; m <<= 1) {
#pragma unroll
        for (int r = 0; r < 4; ++r) {
            psv[r] += __shfl_xor(psv[r], m);
            pdv[r] += __shfl_xor(pdv[r], m);
        }
    }
    if (t16 == 0) {
#pragma unroll
        for (int r = 0; r < 4; ++r) {
            sred[0][og][jg * 16 + q * 4 + r] = psv[r];
            sred[1][og][jg * 16 + q * 4 + r] = pdv[r];
        }
    }
    __syncthreads();
    if (tid < 64) {
        float ss = sred[0][0][tid] + sred[0][1][tid] + sred[0][2][tid] + sred[0][3][tid];
        float dd = sred[1][0][tid] + sred[1][1][tid] + sred[1][2][tid] + sred[1][3][tid];
        s_src[bid * 64 + tid] = ss;
        s_dst[bid * 64 + tid] = dd;
    }
}

// ---------------------------------------------------------------------------
// attn (5x harness-passed, ~22us): bitmask + LDS-staged hT, 1 barrier/chunk,
// 32x32 wave tiles, 1024 threads, grid (8,32).
// ---------------------------------------------------------------------------
__global__ __launch_bounds__(1024) void attn(const ushort_t* __restrict__ hT,
                                             const u64_t* __restrict__ adjb,
                                             const float* __restrict__ s_src,
                                             const float* __restrict__ s_dst,
                                             float* __restrict__ out) {
    const int tid = threadIdx.x;           // 0..1023
    const int w = tid >> 6;                // wave 0..15
    const int lane = tid & 63;
    const int l5 = lane & 31, hi = lane >> 5;
    const int b = blockIdx.x;
    const int i0 = blockIdx.y * 64;

    __shared__ ushort_t hts[2][256][40];   // 256 o x 32 j (+8 pad) : 40 KB
    __shared__ ushort_t ps[2][64][40];     // 64 i x 32 j (+8 pad)  : 10 KB
    __shared__ float sdl[2048];            // s_dst * log2e : 8 KB
    __shared__ float rls[64];              // row sums of p

    // stage s_dst*log2e (2 floats/thread)
    const float* sdb = s_dst + (size_t)b * 2048;
    {
        int idx = tid * 2;
        float2 v = *(const float2*)(sdb + idx);
        v.x *= LOG2E; v.y *= LOG2E;
        *(float2*)(&sdl[idx]) = v;
    }

    // p-producer mapping: i = 4w + (lane>>4), j-pair = lane&15
    const int ip = w * 4 + (lane >> 4);
    const int jp = lane & 15;
    const float si = s_src[(size_t)b * 2048 + i0 + ip] * LOG2E;
    // bitmask row: 32 u64 words (as uint2), word it covers j in [it*64,+64)
    const uint2* amr = (const uint2*)(adjb + ((size_t)b * 2048 + i0 + ip) * 32);

    // hT stage mapping: row = tid>>2, 8-j segment = tid&3 (16 B/thread)
    const int hrow = tid >> 2, hseg = tid & 3;
    const ushort_t* hTg = hT + ((size_t)b * 256 + hrow) * 2048 + hseg * 8;

    // consumer mapping: wave tile 32 i x 32 o
    const int osub = (w & 7) * 32, ih = (w >> 3) * 32;

    floatx16 acc = {};
    float lsum = 0.f;
    int4 hreg;
    uint2 amc, amcN;

    // prologue: hT chunk 0; mask words for chunks 0,1
    hreg = *(const int4*)(hTg);
    amc = amr[0];
    __syncthreads();   // sdl ready

#pragma unroll 1
    for (int it = 0; it < 32; ++it) {
        const int c = it * 2;
        // ================= even chunk c (buf 0, mask amc.x) ================
        *(int4*)(&hts[0][hrow][hseg * 8]) = hreg;
        hreg = *(const int4*)(hTg + (size_t)(c + 1) * 32);        // prefetch c+1
        amcN = amr[(it + 1 < 32) ? it + 1 : 31];                  // prefetch masks
        {
            float2 sd = *(const float2*)(&sdl[c * 32 + jp * 2]);
            unsigned m0 = (amc.x >> (jp * 2)) & 1u;
            unsigned m1 = (amc.x >> (jp * 2 + 1)) & 1u;
            float t0 = si + sd.x;
            float t1 = si + sd.y;
            float l0 = fmaxf(t0, 0.2f * t0);
            float l1 = fmaxf(t1, 0.2f * t1);
            float p0 = __builtin_amdgcn_exp2f(l0);
            float p1 = __builtin_amdgcn_exp2f(l1);
            p0 = m0 ? p0 : 0.0f;
            p1 = m1 ? p1 : 0.0f;
            unsigned short u0 = f2bf(p0);
            unsigned short u1 = f2bf(p1);
            lsum += bf2f(u0) + bf2f(u1);
            *(unsigned*)(&ps[0][ip][jp * 2]) = (unsigned)u0 | ((unsigned)u1 << 16);
        }
        __syncthreads();
#pragma unroll
        for (int ks = 0; ks < 2; ++ks) {
            short8 afr = *(const short8*)(&hts[0][osub + l5][ks * 16 + hi * 8]);
            short8 bfr = *(const short8*)(&ps[0][ih + l5][ks * 16 + hi * 8]);
            acc = __builtin_amdgcn_mfma_f32_32x32x16_bf16(afr, bfr, acc, 0, 0, 0);
        }
        // ================= odd chunk c+1 (buf 1, mask amc.y) ===============
        *(int4*)(&hts[1][hrow][hseg * 8]) = hreg;
        {   // prefetch hT chunk c+2 (clamped in-bounds at tail)
            const int nh = (c + 2 < 64) ? c + 2 : 63;
            hreg = *(const int4*)(hTg + (size_t)nh * 32);
        }
        {
            float2 sd = *(const float2*)(&sdl[(c + 1) * 32 + jp * 2]);
            unsigned m0 = (amc.y >> (jp * 2)) & 1u;
            unsigned m1 = (amc.y >> (jp * 2 + 1)) & 1u;
            float t0 = si + sd.x;
            float t1 = si + sd.y;
            float l0 = fmaxf(t0, 0.2f * t0);
            float l1 = fmaxf(t1, 0.2f * t1);
            float p0 = __builtin_amdgcn_exp2f(l0);
            float p1 = __builtin_amdgcn_exp2f(l1);
            p0 = m0 ? p0 : 0.0f;
            p1 = m1 ? p1 : 0.0f;
            unsigned short u0 = f2bf(p0);
            unsigned short u1 = f2bf(p1);
            lsum += bf2f(u0) + bf2f(u1);
            *(unsigned*)(&ps[1][ip][jp * 2]) = (unsigned)u0 | ((unsigned)u1 << 16);
        }
        __syncthreads();
#pragma unroll
        for (int ks = 0; ks < 2; ++ks) {
            short8 afr = *(const short8*)(&hts[1][osub + l5][ks * 16 + hi * 8]);
            short8 bfr = *(const short8*)(&ps[1][ih + l5][ks * 16 + hi * 8]);
            acc = __builtin_amdgcn_mfma_f32_32x32x16_bf16(afr, bfr, acc, 0, 0, 0);
        }
        amc = amcN;
    }

    // row sums: row ip's full j-range lives in its 16 jp-lanes
#pragma unroll
    for (int m = 1; m < 16; m <<= 1) lsum += __shfl_xor(lsum, m);
    if (jp == 0) rls[ip] = lsum;
    __syncthreads();

    // epilogue: D col=l5 -> i_local, row=(reg&3)+8*(reg>>2)+4*hi -> o_local
    {
        const int i = ih + l5;
        const float s = rls[i];
        const float rl = (s > 0.f) ? 1.0f / s : 0.0f;
        float* orow = out + ((size_t)b * 2048 + i0 + i) * 256 + osub;
#pragma unroll
        for (int rq = 0; rq < 4; ++rq) {
            floatx4 v;
            v[0] = acc[rq * 4 + 0] * rl;
            v[1] = acc[rq * 4 + 1] * rl;
            v[2] = acc[rq * 4 + 2] * rl;
            v[3] = acc[rq * 4 + 3] * rl;
            *(floatx4*)(orow + rq * 8 + hi * 4) = v;
        }
    }
}

extern "C" void kernel_launch(void* const* d_in, const int* in_sizes, int n_in,
                              void* d_out, int out_size, void* d_ws, size_t ws_size,
                              hipStream_t stream) {
    const float* x     = (const float*)d_in[0];
    const int*   adj   = (const int*)d_in[1];
    const float* W     = (const float*)d_in[2];
    const float* a_src = (const float*)d_in[3];
    const float* a_dst = (const float*)d_in[4];
    float* out = (float*)d_out;

    // ws: hT 8MB | s_src 64KB | s_dst 64KB | adjb 4MB = 12.125MB (proven)
    char* ws = (char*)d_ws;
    ushort_t* hT = (ushort_t*)ws;                                   // [0, 8M)
    float* s_src = (float*)(ws + (size_t)8 * 1024 * 1024);          // 64 KB
    float* s_dst = s_src + 16384;                                   // 64 KB
    u64_t* adjb  = (u64_t*)(s_dst + 16384);                         // 4 MB

    adjpack<<<2048, 256, 0, stream>>>(adj, (unsigned char*)adjb);
    gemm_h<<<256, 1024, 0, stream>>>(x, W, hT, a_src, a_dst, s_src, s_dst);
    attn<<<dim3(8, 32), 1024, 0, stream>>>(hT, adjb, s_src, s_dst, out);
}

// Round 12
// 246.320 us; speedup vs baseline: 1.0375x; 1.0375x over previous
//
#include <hip/hip_runtime.h>
#include <hip/hip_bf16.h>
#include <cstdint>
#include <cstddef>

typedef __attribute__((ext_vector_type(8))) short short8;
typedef __attribute__((ext_vector_type(4))) short short4v;
typedef __attribute__((ext_vector_type(4))) float floatx4;
typedef __attribute__((ext_vector_type(16))) float floatx16;
typedef unsigned short ushort_t;
typedef unsigned long long u64_t;

#define LOG2E 1.44269504088896340736f

__device__ __forceinline__ unsigned short f2bf(float f) {
    unsigned u = __float_as_uint(f);
    u += 0x7FFFu + ((u >> 16) & 1u);   // RNE
    return (unsigned short)(u >> 16);
}
__device__ __forceinline__ float bf2f(unsigned short s) {
    return __uint_as_float(((unsigned)s) << 16);
}

// ---------------------------------------------------------------------------
// prep: fused gemm_h + adj byte-pack.  Grid 1280 x 1024 threads.
// EXACT R9 configuration -- the session's measured-best total (244.6us).
// R10 (word-pack: 256B lane stride = 64-line scatter) and R11 (dedicated
// fill-shaped pack: lost the fusion overlap) both regressed vs this.
// The adj stream's ~2.2 TB/s effective ceiling is structural (7 distinct
// implementations converge on it; FETCH_SIZE shows it is L3-served, i.e.
// a read-path latency wall, not HBM BW) -- fusing gemm behind it is the
// best measured mitigation.
//
// blocks [0,256):    gemm_h body: 64j x 256o tile, x+W staged coalesced
//                    into LDS per K-quarter, o-major hT store, s_src/s_dst
//                    via cross-wave LDS reduction.
// blocks [256,1280): lane-local byte-pack: thread reads 8 consecutive ints
//                    (2x int4, dense 16B/lane), emits one mask byte (pure
//                    VALU), stores 1B (64B/wave dense).  Byte b of adjb ==
//                    flat adj bits [8b, 8b+8), little-endian-consistent
//                    with the u64 words attn reads.  No cross-lane ops.
// ---------------------------------------------------------------------------
__global__ __launch_bounds__(1024, 8) void prep(const float* __restrict__ x,
                                                const float* __restrict__ W,
                                                const int* __restrict__ adj,
                                                ushort_t* __restrict__ hT,
                                                const float* __restrict__ a_src,
                                                const float* __restrict__ a_dst,
                                                float* __restrict__ s_src,
                                                float* __restrict__ s_dst,
                                                u64_t* __restrict__ adjb) {
    __shared__ ushort_t wt[256][72];   // W quarter: 256 o x 64 k (+8 pad)
    __shared__ ushort_t xs[64][72];    // x quarter: 64 j x 64 k (+8 pad)
    __shared__ float sred[2][4][64];

    const int tid = threadIdx.x;
    const int w = tid >> 6, lane = tid & 63;

    if (blockIdx.x >= 256) {
        // ------------- lane-local byte pack (1024 blocks) ------------------
        const size_t base = (size_t)(blockIdx.x - 256) * 1024 + tid;
        unsigned char* ab = (unsigned char*)adjb;
#pragma unroll
        for (int i = 0; i < 4; ++i) {
            const size_t bI = base + (size_t)i * (1024 * 1024);
            const int* ap = adj + bI * 8;
            int4 a0 = *(const int4*)(ap);
            int4 a1 = *(const int4*)(ap + 4);
            unsigned v = (a0.x != 0 ? 1u : 0u)   | (a0.y != 0 ? 2u : 0u)  |
                         (a0.z != 0 ? 4u : 0u)   | (a0.w != 0 ? 8u : 0u)  |
                         (a1.x != 0 ? 16u : 0u)  | (a1.y != 0 ? 32u : 0u) |
                         (a1.z != 0 ? 64u : 0u)  | (a1.w != 0 ? 128u : 0u);
            ab[bI] = (unsigned char)v;
        }
        return;
    }

    // ------------------- gemm half (256 blocks) ---------------------------
    const int bid = blockIdx.x;
    const int q = (lane >> 4) & 3, t16 = lane & 15;
    const int jg = w >> 2, og = w & 3;

    floatx4 acc[4] = {};
#pragma unroll
    for (int kp = 0; kp < 4; ++kp) {
        if (kp) __syncthreads();       // protect wt/xs overwrite
        // stage W quarter (fp32 -> bf16), 16 ushorts/thread
#pragma unroll
        for (int r = 0; r < 2; ++r) {
            int G = tid + 1024 * r;
            int row = G >> 3, g = G & 7;
            const float* wsrc = W + (size_t)row * 256 + kp * 64 + g * 8;
            float4 f0 = *(const float4*)(wsrc);
            float4 f1 = *(const float4*)(wsrc + 4);
            short8 wv;
            wv[0] = (short)f2bf(f0.x); wv[1] = (short)f2bf(f0.y);
            wv[2] = (short)f2bf(f0.z); wv[3] = (short)f2bf(f0.w);
            wv[4] = (short)f2bf(f1.x); wv[5] = (short)f2bf(f1.y);
            wv[6] = (short)f2bf(f1.z); wv[7] = (short)f2bf(f1.w);
            *(short8*)(&wt[row][g * 8]) = wv;
        }
        // stage x quarter (coalesced): thread -> (row = tid>>4, 4 k-cols)
        {
            int row = tid >> 4, kc = (tid & 15) * 4;
            float4 xv = *(const float4*)(x + (size_t)(bid * 64 + row) * 256 + kp * 64 + kc);
            short4v s;
            s[0] = (short)f2bf(xv.x); s[1] = (short)f2bf(xv.y);
            s[2] = (short)f2bf(xv.z); s[3] = (short)f2bf(xv.w);
            *(short4v*)(&xs[row][kc]) = s;
        }
        __syncthreads();
#pragma unroll
        for (int ks = 0; ks < 2; ++ks) {
            short8 af = *(const short8*)(&xs[jg * 16 + t16][ks * 32 + q * 8]);
#pragma unroll
            for (int ct = 0; ct < 4; ++ct) {
                short8 bf = *(const short8*)(&wt[og * 64 + ct * 16 + t16][ks * 32 + q * 8]);
                acc[ct] = __builtin_amdgcn_mfma_f32_16x16x32_bf16(af, bf, acc[ct], 0, 0, 0);
            }
        }
    }

    // hT store: D col=t16 -> o_local, row=q*4+r -> j_local  (o-major layout)
    const int jbase = bid * 64 + jg * 16 + q * 4;   // flat b*2048+j
    const int b = jbase >> 11, jj = jbase & 2047;
#pragma unroll
    for (int ct = 0; ct < 4; ++ct) {
        const int o = og * 64 + ct * 16 + t16;
        short4v sv;
        sv[0] = (short)f2bf(acc[ct][0]);
        sv[1] = (short)f2bf(acc[ct][1]);
        sv[2] = (short)f2bf(acc[ct][2]);
        sv[3] = (short)f2bf(acc[ct][3]);
        *(short4v*)(hT + ((size_t)b * 256 + o) * 2048 + jj) = sv;
    }

    // s_src/s_dst partials (this wave's 64 o), 16-lane shuffle
    float psv[4] = {}, pdv[4] = {};
#pragma unroll
    for (int ct = 0; ct < 4; ++ct) {
        const int o = og * 64 + ct * 16 + t16;
        float as = a_src[o], ad = a_dst[o];
#pragma unroll
        for (int r = 0; r < 4; ++r) {
            psv[r] = __fmaf_rn(acc[ct][r], as, psv[r]);
            pdv[r] = __fmaf_rn(acc[ct][r], ad, pdv[r]);
        }
    }
#pragma unroll
    for (int m = 1; m < 16; m <<= 1) {
#pragma unroll
        for (int r = 0; r < 4; ++r) {
            psv[r] += __shfl_xor(psv[r], m);
            pdv[r] += __shfl_xor(pdv[r], m);
        }
    }
    if (t16 == 0) {
#pragma unroll
        for (int r = 0; r < 4; ++r) {
            sred[0][og][jg * 16 + q * 4 + r] = psv[r];
            sred[1][og][jg * 16 + q * 4 + r] = pdv[r];
        }
    }
    __syncthreads();
    if (tid < 64) {
        float ss = sred[0][0][tid] + sred[0][1][tid] + sred[0][2][tid] + sred[0][3][tid];
        float dd = sred[1][0][tid] + sred[1][1][tid] + sred[1][2][tid] + sred[1][3][tid];
        s_src[bid * 64 + tid] = ss;
        s_dst[bid * 64 + tid] = dd;
    }
}

// ---------------------------------------------------------------------------
// attn (R5/R7/R8/R9-verbatim, 5x harness-passed, ~22us): bitmask +
// LDS-staged hT, 1 barrier/chunk, 32x32 wave tiles, 1024 threads, grid (8,32).
// ---------------------------------------------------------------------------
__global__ __launch_bounds__(1024) void attn(const ushort_t* __restrict__ hT,
                                             const u64_t* __restrict__ adjb,
                                             const float* __restrict__ s_src,
                                             const float* __restrict__ s_dst,
                                             float* __restrict__ out) {
    const int tid = threadIdx.x;           // 0..1023
    const int w = tid >> 6;                // wave 0..15
    const int lane = tid & 63;
    const int l5 = lane & 31, hi = lane >> 5;
    const int b = blockIdx.x;
    const int i0 = blockIdx.y * 64;

    __shared__ ushort_t hts[2][256][40];   // 256 o x 32 j (+8 pad) : 40 KB
    __shared__ ushort_t ps[2][64][40];     // 64 i x 32 j (+8 pad)  : 10 KB
    __shared__ float sdl[2048];            // s_dst * log2e : 8 KB
    __shared__ float rls[64];              // row sums of p

    // stage s_dst*log2e (2 floats/thread)
    const float* sdb = s_dst + (size_t)b * 2048;
    {
        int idx = tid * 2;
        float2 v = *(const float2*)(sdb + idx);
        v.x *= LOG2E; v.y *= LOG2E;
        *(float2*)(&sdl[idx]) = v;
    }

    // p-producer mapping: i = 4w + (lane>>4), j-pair = lane&15
    const int ip = w * 4 + (lane >> 4);
    const int jp = lane & 15;
    const float si = s_src[(size_t)b * 2048 + i0 + ip] * LOG2E;
    // bitmask row: 32 u64 words (as uint2), word it covers j in [it*64,+64)
    const uint2* amr = (const uint2*)(adjb + ((size_t)b * 2048 + i0 + ip) * 32);

    // hT stage mapping: row = tid>>2, 8-j segment = tid&3 (16 B/thread)
    const int hrow = tid >> 2, hseg = tid & 3;
    const ushort_t* hTg = hT + ((size_t)b * 256 + hrow) * 2048 + hseg * 8;

    // consumer mapping: wave tile 32 i x 32 o
    const int osub = (w & 7) * 32, ih = (w >> 3) * 32;

    floatx16 acc = {};
    float lsum = 0.f;
    int4 hreg;
    uint2 amc, amcN;

    // prologue: hT chunk 0; mask words for chunks 0,1
    hreg = *(const int4*)(hTg);
    amc = amr[0];
    __syncthreads();   // sdl ready

#pragma unroll 1
    for (int it = 0; it < 32; ++it) {
        const int c = it * 2;
        // ================= even chunk c (buf 0, mask amc.x) ================
        *(int4*)(&hts[0][hrow][hseg * 8]) = hreg;
        hreg = *(const int4*)(hTg + (size_t)(c + 1) * 32);        // prefetch c+1
        amcN = amr[(it + 1 < 32) ? it + 1 : 31];                  // prefetch masks
        {
            float2 sd = *(const float2*)(&sdl[c * 32 + jp * 2]);
            unsigned m0 = (amc.x >> (jp * 2)) & 1u;
            unsigned m1 = (amc.x >> (jp * 2 + 1)) & 1u;
            float t0 = si + sd.x;
            float t1 = si + sd.y;
            float l0 = fmaxf(t0, 0.2f * t0);
            float l1 = fmaxf(t1, 0.2f * t1);
            float p0 = __builtin_amdgcn_exp2f(l0);
            float p1 = __builtin_amdgcn_exp2f(l1);
            p0 = m0 ? p0 : 0.0f;
            p1 = m1 ? p1 : 0.0f;
            unsigned short u0 = f2bf(p0);
            unsigned short u1 = f2bf(p1);
            lsum += bf2f(u0) + bf2f(u1);
            *(unsigned*)(&ps[0][ip][jp * 2]) = (unsigned)u0 | ((unsigned)u1 << 16);
        }
        __syncthreads();
#pragma unroll
        for (int ks = 0; ks < 2; ++ks) {
            short8 afr = *(const short8*)(&hts[0][osub + l5][ks * 16 + hi * 8]);
            short8 bfr = *(const short8*)(&ps[0][ih + l5][ks * 16 + hi * 8]);
            acc = __builtin_amdgcn_mfma_f32_32x32x16_bf16(afr, bfr, acc, 0, 0, 0);
        }
        // ================= odd chunk c+1 (buf 1, mask amc.y) ===============
        *(int4*)(&hts[1][hrow][hseg * 8]) = hreg;
        {   // prefetch hT chunk c+2 (clamped in-bounds at tail)
            const int nh = (c + 2 < 64) ? c + 2 : 63;
            hreg = *(const int4*)(hTg + (size_t)nh * 32);
        }
        {
            float2 sd = *(const float2*)(&sdl[(c + 1) * 32 + jp * 2]);
            unsigned m0 = (amc.y >> (jp * 2)) & 1u;
            unsigned m1 = (amc.y >> (jp * 2 + 1)) & 1u;
            float t0 = si + sd.x;
            float t1 = si + sd.y;
            float l0 = fmaxf(t0, 0.2f * t0);
            float l1 = fmaxf(t1, 0.2f * t1);
            float p0 = __builtin_amdgcn_exp2f(l0);
            float p1 = __builtin_amdgcn_exp2f(l1);
            p0 = m0 ? p0 : 0.0f;
            p1 = m1 ? p1 : 0.0f;
            unsigned short u0 = f2bf(p0);
            unsigned short u1 = f2bf(p1);
            lsum += bf2f(u0) + bf2f(u1);
            *(unsigned*)(&ps[1][ip][jp * 2]) = (unsigned)u0 | ((unsigned)u1 << 16);
        }
        __syncthreads();
#pragma unroll
        for (int ks = 0; ks < 2; ++ks) {
            short8 afr = *(const short8*)(&hts[1][osub + l5][ks * 16 + hi * 8]);
            short8 bfr = *(const short8*)(&ps[1][ih + l5][ks * 16 + hi * 8]);
            acc = __builtin_amdgcn_mfma_f32_32x32x16_bf16(afr, bfr, acc, 0, 0, 0);
        }
        amc = amcN;
    }

    // row sums: row ip's full j-range lives in its 16 jp-lanes
#pragma unroll
    for (int m = 1; m < 16; m <<= 1) lsum += __shfl_xor(lsum, m);
    if (jp == 0) rls[ip] = lsum;
    __syncthreads();

    // epilogue: D col=l5 -> i_local, row=(reg&3)+8*(reg>>2)+4*hi -> o_local
    {
        const int i = ih + l5;
        const float s = rls[i];
        const float rl = (s > 0.f) ? 1.0f / s : 0.0f;
        float* orow = out + ((size_t)b * 2048 + i0 + i) * 256 + osub;
#pragma unroll
        for (int rq = 0; rq < 4; ++rq) {
            floatx4 v;
            v[0] = acc[rq * 4 + 0] * rl;
            v[1] = acc[rq * 4 + 1] * rl;
            v[2] = acc[rq * 4 + 2] * rl;
            v[3] = acc[rq * 4 + 3] * rl;
            *(floatx4*)(orow + rq * 8 + hi * 4) = v;
        }
    }
}

extern "C" void kernel_launch(void* const* d_in, const int* in_sizes, int n_in,
                              void* d_out, int out_size, void* d_ws, size_t ws_size,
                              hipStream_t stream) {
    const float* x     = (const float*)d_in[0];
    const int*   adj   = (const int*)d_in[1];
    const float* W     = (const float*)d_in[2];
    const float* a_src = (const float*)d_in[3];
    const float* a_dst = (const float*)d_in[4];
    float* out = (float*)d_out;

    // ws: hT 8MB | s_src 64KB | s_dst 64KB | adjb 4MB = 12.125MB (proven)
    char* ws = (char*)d_ws;
    ushort_t* hT = (ushort_t*)ws;                                   // [0, 8M)
    float* s_src = (float*)(ws + (size_t)8 * 1024 * 1024);          // 64 KB
    float* s_dst = s_src + 16384;                                   // 64 KB
    u64_t* adjb  = (u64_t*)(s_dst + 16384);                         // 4 MB

    prep<<<1280, 1024, 0, stream>>>(x, W, adj, hT, a_src, a_dst, s_src, s_dst, adjb);
    attn<<<dim3(8, 32), 1024, 0, stream>>>(hT, adjb, s_src, s_dst, out);
}